// Round 1
// baseline (628.478 us; speedup 1.0000x reference)
//
#include <hip/hip_runtime.h>
#include <cmath>

static constexpr int T_DIM = 2000;
static constexpr int N_DIM = 64;
static constexpr int V_DIM = 1000;   // 250 float4 per row
static constexpr int BLANK = 0;

// ---------------------------------------------------------------------------
// Kernel 1: one wave (64 lanes) per (t,n) row. Row is V=1000 contiguous fp32.
// Computes argmax(logits) and maxlogp = -log(sum exp(x - max)).
// Writes transposed (N,T) so kernel 2 reads coalesced.
// ---------------------------------------------------------------------------
__global__ __launch_bounds__(256) void ctc_rowreduce(
    const float* __restrict__ logits,
    float* __restrict__ maxlpT,   // (N, T)
    int*   __restrict__ argmaxT)  // (N, T)
{
    const int lane = threadIdx.x & 63;
    const int wv   = threadIdx.x >> 6;
    const int row  = blockIdx.x * 4 + wv;        // row = t*N + n, always < T*N

    const float4* p = reinterpret_cast<const float4*>(logits + (size_t)row * V_DIM);

    // 250 float4 per row; lanes 0..57 take a 4th chunk
    float4 r0 = p[lane];
    float4 r1 = p[lane + 64];
    float4 r2 = p[lane + 128];
    const bool has3 = (lane < 58);
    float4 r3 = has3 ? p[lane + 192] : make_float4(0.f, 0.f, 0.f, 0.f);

    // local max/argmax, ascending index order => first-occurrence tie-break
    float m = -INFINITY; int mi = 0;
    int b = 4 * lane;
#define UPD(v, idx) do { if ((v) > m) { m = (v); mi = (idx); } } while (0)
    UPD(r0.x, b + 0); UPD(r0.y, b + 1); UPD(r0.z, b + 2); UPD(r0.w, b + 3);
    UPD(r1.x, b + 256); UPD(r1.y, b + 257); UPD(r1.z, b + 258); UPD(r1.w, b + 259);
    UPD(r2.x, b + 512); UPD(r2.y, b + 513); UPD(r2.z, b + 514); UPD(r2.w, b + 515);
    if (has3) {
        UPD(r3.x, b + 768); UPD(r3.y, b + 769); UPD(r3.z, b + 770); UPD(r3.w, b + 771);
    }
#undef UPD

    // wave butterfly reduce: max value, smaller index wins ties (matches jnp.argmax)
    #pragma unroll
    for (int off = 32; off >= 1; off >>= 1) {
        float om = __shfl_xor(m, off, 64);
        int   oi = __shfl_xor(mi, off, 64);
        if (om > m || (om == m && oi < mi)) { m = om; mi = oi; }
    }

    // sum of exp(x - m); max term contributes 1.0 so s in [1, 1000]
    float s = __expf(r0.x - m) + __expf(r0.y - m) + __expf(r0.z - m) + __expf(r0.w - m)
            + __expf(r1.x - m) + __expf(r1.y - m) + __expf(r1.z - m) + __expf(r1.w - m)
            + __expf(r2.x - m) + __expf(r2.y - m) + __expf(r2.z - m) + __expf(r2.w - m);
    if (has3)
        s += __expf(r3.x - m) + __expf(r3.y - m) + __expf(r3.z - m) + __expf(r3.w - m);

    #pragma unroll
    for (int off = 32; off >= 1; off >>= 1)
        s += __shfl_xor(s, off, 64);

    if (lane == 0) {
        const int t = row >> 6;            // row / N_DIM (N=64)
        const int n = row & (N_DIM - 1);
        maxlpT[n * T_DIM + t] = -__logf(s);   // m - (m + log s)
        argmaxT[n * T_DIM + t] = mi;
    }
}

// ---------------------------------------------------------------------------
// Kernel 2: one block (256 threads) per batch element n.
// keep mask -> block scan -> LDS compaction -> outputs.
// Output layout (all float): [ score(N) | paths(T*N, (T,N) order) | out_lens(N) ]
// ---------------------------------------------------------------------------
__global__ __launch_bounds__(256) void ctc_scan(
    const float* __restrict__ maxlpT,
    const int*   __restrict__ argmaxT,
    const int*   __restrict__ in_lens,
    float*       __restrict__ out)
{
    constexpr int CHUNK = 8;               // 256*8 = 2048 >= T
    const int n   = blockIdx.x;
    const int tid = threadIdx.x;
    const int in_len = in_lens[n];
    const int*   am = argmaxT + n * T_DIM;
    const float* ml = maxlpT + n * T_DIM;

    __shared__ int buf[T_DIM];             // compacted path values (8000 B)
    __shared__ int scan[256];
    __shared__ float wsum[4];

    const int t0 = tid * CHUNK;
    int  my_am[CHUNK];
    bool my_keep[CHUNK];
    int cnt = 0;
    float sc = 0.f;
    int prev = (t0 > 0 && t0 < T_DIM) ? am[t0 - 1] : -1;  // -1 never matches 0..V-1

    #pragma unroll
    for (int k = 0; k < CHUNK; ++k) {
        const int t = t0 + k;
        if (t < T_DIM) {
            const int a = am[t];
            my_am[k] = a;
            const bool kp = (a != BLANK) && (t == 0 || a != prev) && (t < in_len);
            my_keep[k] = kp;
            cnt += kp ? 1 : 0;
            if (t < in_len) sc += ml[t];
            prev = a;
        } else {
            my_am[k] = 0;
            my_keep[k] = false;
        }
    }

    scan[tid] = cnt;
    __syncthreads();
    // Hillis-Steele inclusive scan over 256 entries
    for (int off = 1; off < 256; off <<= 1) {
        const int v   = scan[tid];
        const int add = (tid >= off) ? scan[tid - off] : 0;
        __syncthreads();
        scan[tid] = v + add;
        __syncthreads();
    }
    const int base    = scan[tid] - cnt;   // exclusive prefix
    const int out_len = scan[255];

    // scatter kept values into LDS compaction buffer
    int pos = base;
    #pragma unroll
    for (int k = 0; k < CHUNK; ++k) {
        if (my_keep[k]) buf[pos++] = my_am[k];
    }

    // score: wave reduce then cross-wave via LDS
    float ss = sc;
    #pragma unroll
    for (int off = 32; off >= 1; off >>= 1)
        ss += __shfl_xor(ss, off, 64);
    if ((tid & 63) == 0) wsum[tid >> 6] = ss;

    __syncthreads();   // covers buf scatter + wsum

    // paths: compacted inside out_len, raw argmax outside; (T,N) layout
    #pragma unroll
    for (int k = 0; k < CHUNK; ++k) {
        const int t = t0 + k;
        if (t < T_DIM) {
            const int v = (t < out_len) ? buf[t] : my_am[k];
            out[N_DIM + (size_t)t * N_DIM + n] = (float)v;
        }
    }

    if (tid == 0) {
        out[n] = wsum[0] + wsum[1] + wsum[2] + wsum[3];
        out[N_DIM + (size_t)T_DIM * N_DIM + n] = (float)out_len;
    }
}

extern "C" void kernel_launch(void* const* d_in, const int* in_sizes, int n_in,
                              void* d_out, int out_size, void* d_ws, size_t ws_size,
                              hipStream_t stream)
{
    const float* logits  = (const float*)d_in[0];
    const int*   in_lens = (const int*)d_in[1];
    float* out = (float*)d_out;

    float* maxlpT = (float*)d_ws;
    int*   argmaxT = (int*)((char*)d_ws + (size_t)T_DIM * N_DIM * sizeof(float));

    ctc_rowreduce<<<(T_DIM * N_DIM) / 4, 256, 0, stream>>>(logits, maxlpT, argmaxT);
    ctc_scan<<<N_DIM, 256, 0, stream>>>(maxlpT, argmaxT, in_lens, out);
}